// Round 1
// baseline (229.488 us; speedup 1.0000x reference)
//
#include <hip/hip_runtime.h>
#include <hip/hip_bf16.h>

// Problem: B=128, N=4096, D_H=512, D_K=512, D_C=1536
// out[b,n] = softmax_n( 10*tanh( (h_c[b]@W_Q) . (H[b,n]@W_K) / sqrt(512) ) )
// Reassociated: v[b] = W_K @ (h_c[b] @ W_Q);  U[b,n] = H[b,n].v[b]/sqrt(512)

#define B_SZ   128
#define N_SZ   4096
#define D_H    512
#define D_K    512
#define D_C    1536
#define RSQRT_DK 0.04419417382415922f   // 1/sqrt(512)

// ---------------------------------------------------------------------------
// Kernel 1: partial Q.  Q[b,k] = sum_c h_c[b,c] * W_Q[c,k]
// Split c into 8 chunks of 192; grid (16 b-groups of 8, 8 c-chunks).
// Partials Qp[cc][b][k] written into d_out (exactly 524288 floats).
// ---------------------------------------------------------------------------
__global__ __launch_bounds__(256) void qpart_kernel(
    const float* __restrict__ h_c, const float* __restrict__ W_Q,
    float* __restrict__ Qp) {
  const int bg = blockIdx.x;   // 0..15, covers b in [bg*8, bg*8+8)
  const int cc = blockIdx.y;   // 0..7,  covers c in [cc*192, cc*192+192)
  const int t  = threadIdx.x;  // 256 threads, thread owns k = 2t, 2t+1

  __shared__ float hc[8 * 192];
  for (int i = t; i < 8 * 192; i += 256) {
    int bi = i / 192, ci = i % 192;
    hc[i] = h_c[(size_t)(bg * 8 + bi) * D_C + cc * 192 + ci];
  }
  __syncthreads();

  float2 acc[8];
#pragma unroll
  for (int bi = 0; bi < 8; ++bi) { acc[bi].x = 0.f; acc[bi].y = 0.f; }

  const int k2 = 2 * t;
#pragma unroll 4
  for (int ci = 0; ci < 192; ++ci) {
    const float2 w = *reinterpret_cast<const float2*>(
        W_Q + (size_t)(cc * 192 + ci) * D_K + k2);
#pragma unroll
    for (int bi = 0; bi < 8; ++bi) {
      const float h = hc[bi * 192 + ci];
      acc[bi].x += h * w.x;
      acc[bi].y += h * w.y;
    }
  }

#pragma unroll
  for (int bi = 0; bi < 8; ++bi) {
    *reinterpret_cast<float2*>(
        Qp + ((size_t)cc * B_SZ + bg * 8 + bi) * D_K + k2) = acc[bi];
  }
}

// ---------------------------------------------------------------------------
// Kernel 2: v[b,d] = sum_k Q[b,k] * W_K[d,k]
// Grid (128 b, 32 d-chunks of 16). Block stages Q[b] (reducing 8 partials)
// into LDS, then 4 waves x 4 d each: wave-per-d dot over W_K row (coalesced).
// ---------------------------------------------------------------------------
__global__ __launch_bounds__(256) void vcomp_kernel(
    const float* __restrict__ Qp, const float* __restrict__ W_K,
    float* __restrict__ v) {
  const int b  = blockIdx.x;
  const int dc = blockIdx.y;
  const int t  = threadIdx.x;

  __shared__ float q[D_K];
  for (int i = t; i < D_K; i += 256) {
    float s = 0.f;
#pragma unroll
    for (int cc = 0; cc < 8; ++cc)
      s += Qp[((size_t)cc * B_SZ + b) * D_K + i];
    q[i] = s;
  }
  __syncthreads();

  const int wave = t >> 6, lane = t & 63;
  const float4 q0 = *reinterpret_cast<const float4*>(&q[lane * 8]);
  const float4 q1 = *reinterpret_cast<const float4*>(&q[lane * 8 + 4]);

#pragma unroll
  for (int j = 0; j < 4; ++j) {
    const int d = dc * 16 + wave * 4 + j;
    const float4* wp =
        reinterpret_cast<const float4*>(W_K + (size_t)d * D_K + lane * 8);
    const float4 w0 = wp[0], w1 = wp[1];
    float dot = q0.x * w0.x + q0.y * w0.y + q0.z * w0.z + q0.w * w0.w +
                q1.x * w1.x + q1.y * w1.y + q1.z * w1.z + q1.w * w1.w;
#pragma unroll
    for (int off = 32; off; off >>= 1) dot += __shfl_xor(dot, off, 64);
    if (lane == 0) v[(size_t)b * D_H + d] = dot;
  }
}

// ---------------------------------------------------------------------------
// Kernel 3 (the big one): e[b,n] = exp(10*tanh(H[b,n].v[b]/sqrt(512)) - 10)
// Streams H (1.07 GB). One wave per row, 8 rows per wave, 4 waves per block.
// 32 consecutive rows per block -> all share the same b (32 | 4096).
// ---------------------------------------------------------------------------
__global__ __launch_bounds__(256) void score_kernel(
    const float* __restrict__ H, const float* __restrict__ v,
    float* __restrict__ out) {
  const int t = threadIdx.x;
  const int wave = t >> 6, lane = t & 63;
  const size_t row0 = (size_t)blockIdx.x * 32 + wave * 8;
  const int b = (int)(row0 >> 12);

  const float4* vp =
      reinterpret_cast<const float4*>(v + (size_t)b * D_H + lane * 8);
  const float4 v0 = vp[0], v1 = vp[1];

#pragma unroll
  for (int r = 0; r < 8; ++r) {
    const size_t row = row0 + r;
    const float4* hp =
        reinterpret_cast<const float4*>(H + row * D_H + lane * 8);
    const float4 h0 = hp[0], h1 = hp[1];
    float dot = h0.x * v0.x + h0.y * v0.y + h0.z * v0.z + h0.w * v0.w +
                h1.x * v1.x + h1.y * v1.y + h1.z * v1.z + h1.w * v1.w;
#pragma unroll
    for (int off = 32; off; off >>= 1) dot += __shfl_xor(dot, off, 64);
    if (lane == 0) {
      const float u = dot * RSQRT_DK;
      out[row] = expf(10.0f * tanhf(u) - 10.0f);
    }
  }
}

// ---------------------------------------------------------------------------
// Kernel 4: per-batch normalize in place: out[b,:] /= sum(out[b,:])
// One block per b; deterministic tree reduction.
// ---------------------------------------------------------------------------
__global__ __launch_bounds__(256) void norm_kernel(float* __restrict__ out) {
  const int b = blockIdx.x;
  const int t = threadIdx.x;
  float* p = out + (size_t)b * N_SZ;

  float4 x[4];
  float s = 0.f;
#pragma unroll
  for (int j = 0; j < 4; ++j) {
    x[j] = *reinterpret_cast<const float4*>(p + 4 * (t + 256 * j));
    s += x[j].x + x[j].y + x[j].z + x[j].w;
  }

  __shared__ float red[256];
  red[t] = s;
  __syncthreads();
  for (int off = 128; off; off >>= 1) {
    if (t < off) red[t] += red[t + off];
    __syncthreads();
  }
  const float inv = 1.0f / red[0];

#pragma unroll
  for (int j = 0; j < 4; ++j) {
    x[j].x *= inv; x[j].y *= inv; x[j].z *= inv; x[j].w *= inv;
    *reinterpret_cast<float4*>(p + 4 * (t + 256 * j)) = x[j];
  }
}

// ---------------------------------------------------------------------------
extern "C" void kernel_launch(void* const* d_in, const int* in_sizes, int n_in,
                              void* d_out, int out_size, void* d_ws,
                              size_t ws_size, hipStream_t stream) {
  const float* h_c = (const float*)d_in[0];  // [128, 1, 1536]
  const float* H   = (const float*)d_in[1];  // [128, 4096, 512]
  const float* W_Q = (const float*)d_in[2];  // [1536, 512]
  const float* W_K = (const float*)d_in[3];  // [512, 512]

  float* out = (float*)d_out;                // [128, 4096] = 524288 floats
  float* Qp  = (float*)d_out;                // reuse d_out for Q partials
                                             // (8*128*512 = 524288 floats)
  float* v   = (float*)d_ws;                 // [128, 512] = 256 KB scratch

  // 1) Q partials: Qp[cc][b][k]
  qpart_kernel<<<dim3(16, 8), 256, 0, stream>>>(h_c, W_Q, Qp);
  // 2) v[b,d] = Q[b,:] . W_K[d,:]
  vcomp_kernel<<<dim3(128, 32), 256, 0, stream>>>(Qp, W_K, v);
  // 3) e[b,n] = exp(10*tanh(H[b,n].v[b]/sqrt(512)) - 10)  (overwrites d_out)
  score_kernel<<<dim3(16384), 256, 0, stream>>>(H, v, out);
  // 4) softmax normalize per b, in place
  norm_kernel<<<dim3(128), 256, 0, stream>>>(out);
}